// Round 11
// baseline (203.540 us; speedup 1.0000x reference)
//
#include <hip/hip_runtime.h>
#include <hip/hip_bf16.h>
#include <math.h>

#define N_POINTS 32
#define SPACE_DIM 16
#define EMB 512
#define THRESH 0.1f
#define MAX_ITER 10

// log2-domain constants
#define NEG10LOG2E -14.42695040888963f   // -10*log2(e): C -> Crow2
#define EPS_LN2     0.0693147180559945f  // eps*ln2
#define LOGMU2     -4.99999953834f       // log2(1/32 + 1e-8)

typedef _Float16 half8 __attribute__((ext_vector_type(8)));
typedef _Float16 half4 __attribute__((ext_vector_type(4)));
typedef float floatx4 __attribute__((ext_vector_type(4)));

#define BSTRIDE 264   // halves; 528 B rows -> b128-aligned, 2-way max (free)

// ---------------- Fused GEMM: Z = X @ W (fp32 in, f16 MFMA, fp32 out) -------
__global__ __launch_bounds__(256) void gemm_fused(
    const float* __restrict__ X, const float* __restrict__ W,
    float* __restrict__ Z, int M, int K, int N, unsigned* __restrict__ counter)
{
    // zero the err_final counter (visible to err_final via kernel boundary)
    if (blockIdx.x == 0 && blockIdx.y == 0 && threadIdx.x == 0) counter[0] = 0u;

    __shared__ _Float16 Bs[64][BSTRIDE];   // [n][k]

    int t = threadIdx.x;
    int n0 = blockIdx.y * 64;

    // stage W-tile (256k x 64n fp32) -> Bs[n][k] f16, 4x4 sub-blocks
    #pragma unroll
    for (int s = 0; s < 4; ++s) {
        int u = s * 256 + t;
        int nb = u & 15;          // n-group (4 cols)
        int kb = u >> 4;          // k-group (4 rows)
        float4 r0v = *(const float4*)&W[(size_t)(kb * 4 + 0) * N + n0 + nb * 4];
        float4 r1v = *(const float4*)&W[(size_t)(kb * 4 + 1) * N + n0 + nb * 4];
        float4 r2v = *(const float4*)&W[(size_t)(kb * 4 + 2) * N + n0 + nb * 4];
        float4 r3v = *(const float4*)&W[(size_t)(kb * 4 + 3) * N + n0 + nb * 4];
        float c0[4] = {r0v.x, r0v.y, r0v.z, r0v.w};
        float c1[4] = {r1v.x, r1v.y, r1v.z, r1v.w};
        float c2[4] = {r2v.x, r2v.y, r2v.z, r2v.w};
        float c3[4] = {r3v.x, r3v.y, r3v.z, r3v.w};
        #pragma unroll
        for (int c = 0; c < 4; ++c) {
            half4 h = {(_Float16)c0[c], (_Float16)c1[c],
                       (_Float16)c2[c], (_Float16)c3[c]};
            *(half4*)&Bs[nb * 4 + c][kb * 4] = h;
        }
    }
    __syncthreads();

    int wave = t >> 6;
    int lane = t & 63;
    int quad = lane >> 4;
    int l16 = lane & 15;

    int mrow = blockIdx.x * 64 + wave * 16 + l16;
    int msafe = mrow < M ? mrow : M - 1;
    const float4* xp = (const float4*)(X + (size_t)msafe * K);

    floatx4 acc[4] = {{0.f,0.f,0.f,0.f},{0.f,0.f,0.f,0.f},
                      {0.f,0.f,0.f,0.f},{0.f,0.f,0.f,0.f}};

    for (int k0 = 0; k0 < K; k0 += 32) {
        float4 lo = xp[(k0 >> 2) + quad * 2];
        float4 hi = xp[(k0 >> 2) + quad * 2 + 1];
        half8 a = {(_Float16)lo.x, (_Float16)lo.y, (_Float16)lo.z, (_Float16)lo.w,
                   (_Float16)hi.x, (_Float16)hi.y, (_Float16)hi.z, (_Float16)hi.w};
        #pragma unroll
        for (int ct = 0; ct < 4; ++ct) {
            half8 b = *(const half8*)&Bs[ct * 16 + l16][k0 + quad * 8];
            acc[ct] = __builtin_amdgcn_mfma_f32_16x16x32_f16(a, b, acc[ct], 0, 0, 0);
        }
    }

    int rbase = blockIdx.x * 64 + wave * 16 + quad * 4;
    #pragma unroll
    for (int ct = 0; ct < 4; ++ct) {
        int col = n0 + ct * 16 + l16;
        #pragma unroll
        for (int r = 0; r < 4; ++r) {
            int row = rbase + r;
            if (row < M) Z[(size_t)row * N + col] = acc[ct][r];
        }
    }
}

// ---------------- Fused Sinkhorn: 4 edges/block, 1 wave/edge, log2 domain ---
// Exact R9 loop body (proven 52.3 us). Only change: __launch_bounds__(256, 8)
// so all 2048 blocks are co-resident (8 blocks/CU; LDS 8*19456 B = 155.6 KB
// of 160 KB, VGPR budget 64 >= the 52 this kernel uses).
#define WPB 4

__global__ __launch_bounds__(256, 8) void sinkhorn_fused(
    const float* __restrict__ Z,
    const int* __restrict__ ep, const int* __restrict__ en,
    int nE,
    float* __restrict__ err_part,   // [MAX_ITER][2nE]
    float* __restrict__ cost_all)   // [MAX_ITER][2nE]
{
    __shared__ float shm[WPB][32 * 36];  // union: sb=32x20, csh=32x36
    __shared__ float uvs[WPB][64];       // U2[0:32], V2[32:64]

    int tid = threadIdx.x;
    int wv = tid >> 6;
    int t = tid & 63;
    int b = blockIdx.x * WPB + wv;

    int side = (b >= nE) ? 1 : 0;
    int e = b - side * nE;
    const int* edges = side ? en : ep;
    int nx = edges[e];
    int ny = edges[e + nE];

    int c = t & 31;
    int h = t >> 5;
    int r0 = h * 16;

    float* sb  = shm[wv];
    float* csh = shm[wv];
    float* Ul  = uvs[wv];
    float* Vl  = uvs[wv] + 32;

    // stage b point rows into LDS, padded stride 20
    {
        const float4* zb4 = (const float4*)(Z + (size_t)ny * EMB);
        float4 q0 = zb4[t * 2];
        float4 q1 = zb4[t * 2 + 1];
        float* dst = sb + (t >> 1) * 20 + (t & 1) * 8;
        ((float4*)dst)[0] = q0;
        ((float4*)dst)[1] = q1;
    }
    // own a-row in registers
    float areg[16];
    {
        const float4* za4 = (const float4*)(Z + (size_t)nx * EMB + c * SPACE_DIM);
        float4 a0 = za4[0], a1 = za4[1], a2 = za4[2], a3 = za4[3];
        areg[0]=a0.x; areg[1]=a0.y; areg[2]=a0.z; areg[3]=a0.w;
        areg[4]=a1.x; areg[5]=a1.y; areg[6]=a1.z; areg[7]=a1.w;
        areg[8]=a2.x; areg[9]=a2.y; areg[10]=a2.z; areg[11]=a2.w;
        areg[12]=a3.x; areg[13]=a3.y; areg[14]=a3.z; areg[15]=a3.w;
    }

    // Crow[jj] = -10*log2e * ||a_c - b_{r0+jj}||^2
    float Crow[16];
    #pragma unroll
    for (int jj = 0; jj < 16; ++jj) {
        const float* bp = sb + (r0 + jj) * 20;
        float s = 0.f;
        #pragma unroll
        for (int d = 0; d < SPACE_DIM; ++d) {
            float diff = areg[d] - bp[d];
            s = fmaf(diff, diff, s);
        }
        Crow[jj] = s * NEG10LOG2E;
    }
    // transpose through LDS (stride 36) to get column fragment
    #pragma unroll
    for (int g = 0; g < 4; ++g) {
        *(float4*)&csh[c * 36 + r0 + g * 4] =
            make_float4(Crow[g*4+0], Crow[g*4+1], Crow[g*4+2], Crow[g*4+3]);
    }
    float Ccol[16];
    #pragma unroll
    for (int ii = 0; ii < 16; ++ii)
        Ccol[ii] = csh[(r0 + ii) * 36 + c];

    Vl[c] = 0.f;
    float U = 0.f;

    for (int it = 0; it < MAX_ITER; ++it) {
        // ---- row pass ----
        float w[16];
        {
            const float4* vp = (const float4*)(Vl + r0);
            float4 v0 = vp[0], v1 = vp[1], v2 = vp[2], v3 = vp[3];
            float vv[16] = {v0.x,v0.y,v0.z,v0.w, v1.x,v1.y,v1.z,v1.w,
                            v2.x,v2.y,v2.z,v2.w, v3.x,v3.y,v3.z,v3.w};
            #pragma unroll
            for (int jj = 0; jj < 16; ++jj) w[jj] = Crow[jj] + vv[jj];
        }
        // pairwise max tree
        float m8[8];
        #pragma unroll
        for (int k = 0; k < 8; ++k) m8[k] = fmaxf(w[k], w[k + 8]);
        float m4a = fmaxf(m8[0], m8[4]), m4b = fmaxf(m8[1], m8[5]);
        float m4c = fmaxf(m8[2], m8[6]), m4d = fmaxf(m8[3], m8[7]);
        float mx = fmaxf(fmaxf(m4a, m4b), fmaxf(m4c, m4d));
        mx = fmaxf(mx, __shfl_xor(mx, 32));

        float ex[16];
        #pragma unroll
        for (int jj = 0; jj < 16; ++jj) ex[jj] = __builtin_amdgcn_exp2f(w[jj] - mx);
        // pairwise sum trees for sm and pc
        float s8[8], p8[8];
        #pragma unroll
        for (int k = 0; k < 8; ++k) {
            s8[k] = ex[k] + ex[k + 8];
            p8[k] = fmaf(ex[k], Crow[k], ex[k + 8] * Crow[k + 8]);
        }
        float sm = ((s8[0]+s8[4]) + (s8[1]+s8[5])) + ((s8[2]+s8[6]) + (s8[3]+s8[7]));
        float pc = ((p8[0]+p8[4]) + (p8[1]+p8[5])) + ((p8[2]+p8[6]) + (p8[3]+p8[7]));
        sm += __shfl_xor(sm, 32);

        // cost of state after `it` iterations (pre-update U; V just read)
        float cc = (it > 0) ? __builtin_amdgcn_exp2f(U + mx) * pc : 0.f;

        float Un = LOGMU2 - (mx + __builtin_amdgcn_logf(sm));
        float du = fabsf(Un - U);   // identical in both halves

        // interleaved butterflies: du needs 5 levels, cc needs 6
        #pragma unroll
        for (int m = 1; m < 32; m <<= 1) {
            du += __shfl_xor(du, m);
            cc += __shfl_xor(cc, m);
        }
        cc += __shfl_xor(cc, 32);

        if (t == 0) {
            err_part[(size_t)it * (2 * nE) + b] = EPS_LN2 * du;
            if (it > 0)
                cost_all[(size_t)(it - 1) * (2 * nE) + b] = -EPS_LN2 * cc;
        }
        U = Un;
        Ul[c] = U;

        // ---- col pass ----
        float wc[16];
        {
            const float4* up = (const float4*)(Ul + r0);
            float4 u0 = up[0], u1 = up[1], u2 = up[2], u3 = up[3];
            float uu[16] = {u0.x,u0.y,u0.z,u0.w, u1.x,u1.y,u1.z,u1.w,
                            u2.x,u2.y,u2.z,u2.w, u3.x,u3.y,u3.z,u3.w};
            #pragma unroll
            for (int ii = 0; ii < 16; ++ii) wc[ii] = Ccol[ii] + uu[ii];
        }
        float n8[8];
        #pragma unroll
        for (int k = 0; k < 8; ++k) n8[k] = fmaxf(wc[k], wc[k + 8]);
        float n4a = fmaxf(n8[0], n8[4]), n4b = fmaxf(n8[1], n8[5]);
        float n4c = fmaxf(n8[2], n8[6]), n4d = fmaxf(n8[3], n8[7]);
        float mx2 = fmaxf(fmaxf(n4a, n4b), fmaxf(n4c, n4d));
        mx2 = fmaxf(mx2, __shfl_xor(mx2, 32));

        float e2[16];
        #pragma unroll
        for (int ii = 0; ii < 16; ++ii) e2[ii] = __builtin_amdgcn_exp2f(wc[ii] - mx2);
        float t8[8];
        #pragma unroll
        for (int k = 0; k < 8; ++k) t8[k] = e2[k] + e2[k + 8];
        float sm2 = ((t8[0]+t8[4]) + (t8[1]+t8[5])) + ((t8[2]+t8[6]) + (t8[3]+t8[7]));
        sm2 += __shfl_xor(sm2, 32);
        float Vn = LOGMU2 - (mx2 + __builtin_amdgcn_logf(sm2));
        Vl[c] = Vn;
    }

    // final-state cost (after MAX_ITER iterations) -> index MAX_ITER-1
    {
        const float4* vp = (const float4*)(Vl + r0);
        float4 v0 = vp[0], v1 = vp[1], v2 = vp[2], v3 = vp[3];
        float vv[16] = {v0.x,v0.y,v0.z,v0.w, v1.x,v1.y,v1.z,v1.w,
                        v2.x,v2.y,v2.z,v2.w, v3.x,v3.y,v3.z,v3.w};
        float cc = 0.f;
        #pragma unroll
        for (int jj = 0; jj < 16; ++jj)
            cc = fmaf(__builtin_amdgcn_exp2f(U + Crow[jj] + vv[jj]), Crow[jj], cc);
        #pragma unroll
        for (int m = 1; m < 64; m <<= 1) cc += __shfl_xor(cc, m);
        if (t == 0)
            cost_all[(size_t)(MAX_ITER - 1) * (2 * nE) + b] = -EPS_LN2 * cc;
    }
}

// ---------------- err reduce + final loss, last-block pattern (20 blocks) ---
__global__ __launch_bounds__(256) void err_final(
    const float* __restrict__ err_part, const float* __restrict__ cost_all,
    float* __restrict__ err_mean, unsigned* __restrict__ counter,
    float* __restrict__ out, int nE)
{
    __shared__ float red[256];
    __shared__ int is_last;

    int side = blockIdx.x / MAX_ITER;
    int it = blockIdx.x - side * MAX_ITER;
    const float* p = err_part + (size_t)it * (2 * nE) + side * nE;
    float s = 0.f;
    for (int idx = threadIdx.x; idx < nE; idx += 256) s += p[idx];
    red[threadIdx.x] = s;
    __syncthreads();
    for (int stride = 128; stride > 0; stride >>= 1) {
        if (threadIdx.x < stride) red[threadIdx.x] += red[threadIdx.x + stride];
        __syncthreads();
    }
    if (threadIdx.x == 0) {
        __hip_atomic_store(&err_mean[side * MAX_ITER + it], red[0] / (float)nE,
                           __ATOMIC_RELAXED, __HIP_MEMORY_SCOPE_AGENT);
        __threadfence();
        unsigned old = __hip_atomic_fetch_add(counter, 1u, __ATOMIC_ACQ_REL,
                                              __HIP_MEMORY_SCOPE_AGENT);
        is_last = (old == 2 * MAX_ITER - 1);
    }
    __syncthreads();
    if (!is_last) return;

    float em[2 * MAX_ITER];
    #pragma unroll
    for (int i = 0; i < 2 * MAX_ITER; ++i)
        em[i] = __hip_atomic_load(&err_mean[i], __ATOMIC_RELAXED,
                                  __HIP_MEMORY_SCOPE_AGENT);
    int Tp = MAX_ITER, Tn = MAX_ITER;
    for (int i = 0; i < MAX_ITER; ++i)
        if (em[i] < THRESH) { Tp = i + 1; break; }
    for (int i = 0; i < MAX_ITER; ++i)
        if (em[MAX_ITER + i] < THRESH) { Tn = i + 1; break; }

    float acc = 0.f;
    for (int b = threadIdx.x; b < 2 * nE; b += 256) {
        int sd = (b >= nE) ? 1 : 0;
        int T = sd ? Tn : Tp;
        float cost = cost_all[(size_t)(T - 1) * (2 * nE) + b];
        acc += sd ? expf(-cost) : cost * cost;
    }
    __syncthreads();
    red[threadIdx.x] = acc;
    __syncthreads();
    for (int stride = 128; stride > 0; stride >>= 1) {
        if (threadIdx.x < stride) red[threadIdx.x] += red[threadIdx.x + stride];
        __syncthreads();
    }
    if (threadIdx.x == 0) out[0] = red[0] / (float)nE;
}

extern "C" void kernel_launch(void* const* d_in, const int* in_sizes, int n_in,
                              void* d_out, int out_size, void* d_ws, size_t ws_size,
                              hipStream_t stream)
{
    const float* X = (const float*)d_in[0];
    const float* W = (const float*)d_in[1];
    const int* ep = (const int*)d_in[2];
    const int* en = (const int*)d_in[3];
    float* out = (float*)d_out;

    int K = in_sizes[1] / EMB;     // 256
    int M = in_sizes[0] / K;       // 10000
    int nE = in_sizes[2] / 2;      // 4096

    float* ws = (float*)d_ws;
    float* Z = ws;                                          // M*EMB f32
    float* err_part = Z + (size_t)M * EMB;                  // MAX_ITER*2nE
    float* cost_all = err_part + (size_t)MAX_ITER * 2 * nE; // MAX_ITER*2nE
    float* err_mean = cost_all + (size_t)MAX_ITER * 2 * nE; // 32 (20 used)
    unsigned* counter = (unsigned*)(err_mean + 32);         // 1 u32

    dim3 gg((M + 63) / 64, EMB / 64);
    gemm_fused<<<gg, 256, 0, stream>>>(X, W, Z, M, K, EMB, counter);

    int nblk = (2 * nE) / WPB;
    sinkhorn_fused<<<nblk, 64 * WPB, 0, stream>>>(Z, ep, en, nE, err_part, cost_all);

    err_final<<<2 * MAX_ITER, 256, 0, stream>>>(err_part, cost_all, err_mean,
                                                counter, out, nE);
}

// Round 12
// 147.263 us; speedup vs baseline: 1.3822x; 1.3822x over previous
//
#include <hip/hip_runtime.h>
#include <hip/hip_bf16.h>
#include <math.h>

#define N_POINTS 32
#define SPACE_DIM 16
#define EMB 512
#define THRESH 0.1f
#define MAX_ITER 10

// log2-domain constants
#define NEG10LOG2E -14.42695040888963f   // -10*log2(e): C -> Crow2
#define EPS_LN2     0.0693147180559945f  // eps*ln2
#define LOGMU2     -4.99999953834f       // log2(1/32 + 1e-8)

typedef _Float16 half8 __attribute__((ext_vector_type(8)));
typedef _Float16 half4 __attribute__((ext_vector_type(4)));
typedef float floatx4 __attribute__((ext_vector_type(4)));

#define BSTRIDE 264   // halves; 528 B rows -> b128-aligned, 2-way max (free)

// ---------------- Fused GEMM: Z = X @ W (fp32 in, f16 MFMA, fp32 out) -------
__global__ __launch_bounds__(256) void gemm_fused(
    const float* __restrict__ X, const float* __restrict__ W,
    float* __restrict__ Z, int M, int K, int N, unsigned* __restrict__ counter)
{
    // zero the err_final counter (visible to err_final via kernel boundary)
    if (blockIdx.x == 0 && blockIdx.y == 0 && threadIdx.x == 0) counter[0] = 0u;

    __shared__ _Float16 Bs[64][BSTRIDE];   // [n][k]

    int t = threadIdx.x;
    int n0 = blockIdx.y * 64;

    // stage W-tile (256k x 64n fp32) -> Bs[n][k] f16, 4x4 sub-blocks
    #pragma unroll
    for (int s = 0; s < 4; ++s) {
        int u = s * 256 + t;
        int nb = u & 15;          // n-group (4 cols)
        int kb = u >> 4;          // k-group (4 rows)
        float4 r0v = *(const float4*)&W[(size_t)(kb * 4 + 0) * N + n0 + nb * 4];
        float4 r1v = *(const float4*)&W[(size_t)(kb * 4 + 1) * N + n0 + nb * 4];
        float4 r2v = *(const float4*)&W[(size_t)(kb * 4 + 2) * N + n0 + nb * 4];
        float4 r3v = *(const float4*)&W[(size_t)(kb * 4 + 3) * N + n0 + nb * 4];
        float c0[4] = {r0v.x, r0v.y, r0v.z, r0v.w};
        float c1[4] = {r1v.x, r1v.y, r1v.z, r1v.w};
        float c2[4] = {r2v.x, r2v.y, r2v.z, r2v.w};
        float c3[4] = {r3v.x, r3v.y, r3v.z, r3v.w};
        #pragma unroll
        for (int c = 0; c < 4; ++c) {
            half4 h = {(_Float16)c0[c], (_Float16)c1[c],
                       (_Float16)c2[c], (_Float16)c3[c]};
            *(half4*)&Bs[nb * 4 + c][kb * 4] = h;
        }
    }
    __syncthreads();

    int wave = t >> 6;
    int lane = t & 63;
    int quad = lane >> 4;
    int l16 = lane & 15;

    int mrow = blockIdx.x * 64 + wave * 16 + l16;
    int msafe = mrow < M ? mrow : M - 1;
    const float4* xp = (const float4*)(X + (size_t)msafe * K);

    floatx4 acc[4] = {{0.f,0.f,0.f,0.f},{0.f,0.f,0.f,0.f},
                      {0.f,0.f,0.f,0.f},{0.f,0.f,0.f,0.f}};

    for (int k0 = 0; k0 < K; k0 += 32) {
        float4 lo = xp[(k0 >> 2) + quad * 2];
        float4 hi = xp[(k0 >> 2) + quad * 2 + 1];
        half8 a = {(_Float16)lo.x, (_Float16)lo.y, (_Float16)lo.z, (_Float16)lo.w,
                   (_Float16)hi.x, (_Float16)hi.y, (_Float16)hi.z, (_Float16)hi.w};
        #pragma unroll
        for (int ct = 0; ct < 4; ++ct) {
            half8 b = *(const half8*)&Bs[ct * 16 + l16][k0 + quad * 8];
            acc[ct] = __builtin_amdgcn_mfma_f32_16x16x32_f16(a, b, acc[ct], 0, 0, 0);
        }
    }

    int rbase = blockIdx.x * 64 + wave * 16 + quad * 4;
    #pragma unroll
    for (int ct = 0; ct < 4; ++ct) {
        int col = n0 + ct * 16 + l16;
        #pragma unroll
        for (int r = 0; r < 4; ++r) {
            int row = rbase + r;
            if (row < M) Z[(size_t)row * N + col] = acc[ct][r];
        }
    }
}

// ---------------- Fused Sinkhorn: 4 edges/block, 1 wave/edge, log2 domain ---
// ZERO atomics, ZERO barriers. Exact R9 configuration: __launch_bounds__(256,4)
// (VGPR 52, no spill — (256,8) forced VGPR 32 + scratch spill, 2x slower).
#define WPB 4

__global__ __launch_bounds__(256, 4) void sinkhorn_fused(
    const float* __restrict__ Z,
    const int* __restrict__ ep, const int* __restrict__ en,
    int nE,
    float* __restrict__ err_part,   // [MAX_ITER][2nE]
    float* __restrict__ cost_all)   // [MAX_ITER][2nE]
{
    __shared__ float shm[WPB][32 * 36];  // union: sb=32x20, csh=32x36
    __shared__ float uvs[WPB][64];       // U2[0:32], V2[32:64]

    int tid = threadIdx.x;
    int wv = tid >> 6;
    int t = tid & 63;
    int b = blockIdx.x * WPB + wv;

    int side = (b >= nE) ? 1 : 0;
    int e = b - side * nE;
    const int* edges = side ? en : ep;
    int nx = edges[e];
    int ny = edges[e + nE];

    int c = t & 31;
    int h = t >> 5;
    int r0 = h * 16;

    float* sb  = shm[wv];
    float* csh = shm[wv];
    float* Ul  = uvs[wv];
    float* Vl  = uvs[wv] + 32;

    // stage b point rows into LDS, padded stride 20
    {
        const float4* zb4 = (const float4*)(Z + (size_t)ny * EMB);
        float4 q0 = zb4[t * 2];
        float4 q1 = zb4[t * 2 + 1];
        float* dst = sb + (t >> 1) * 20 + (t & 1) * 8;
        ((float4*)dst)[0] = q0;
        ((float4*)dst)[1] = q1;
    }
    // own a-row in registers
    float areg[16];
    {
        const float4* za4 = (const float4*)(Z + (size_t)nx * EMB + c * SPACE_DIM);
        float4 a0 = za4[0], a1 = za4[1], a2 = za4[2], a3 = za4[3];
        areg[0]=a0.x; areg[1]=a0.y; areg[2]=a0.z; areg[3]=a0.w;
        areg[4]=a1.x; areg[5]=a1.y; areg[6]=a1.z; areg[7]=a1.w;
        areg[8]=a2.x; areg[9]=a2.y; areg[10]=a2.z; areg[11]=a2.w;
        areg[12]=a3.x; areg[13]=a3.y; areg[14]=a3.z; areg[15]=a3.w;
    }

    // Crow[jj] = -10*log2e * ||a_c - b_{r0+jj}||^2
    float Crow[16];
    #pragma unroll
    for (int jj = 0; jj < 16; ++jj) {
        const float* bp = sb + (r0 + jj) * 20;
        float s = 0.f;
        #pragma unroll
        for (int d = 0; d < SPACE_DIM; ++d) {
            float diff = areg[d] - bp[d];
            s = fmaf(diff, diff, s);
        }
        Crow[jj] = s * NEG10LOG2E;
    }
    // transpose through LDS (stride 36) to get column fragment
    #pragma unroll
    for (int g = 0; g < 4; ++g) {
        *(float4*)&csh[c * 36 + r0 + g * 4] =
            make_float4(Crow[g*4+0], Crow[g*4+1], Crow[g*4+2], Crow[g*4+3]);
    }
    float Ccol[16];
    #pragma unroll
    for (int ii = 0; ii < 16; ++ii)
        Ccol[ii] = csh[(r0 + ii) * 36 + c];

    Vl[c] = 0.f;
    float U = 0.f;

    for (int it = 0; it < MAX_ITER; ++it) {
        // ---- row pass ----
        float w[16];
        {
            const float4* vp = (const float4*)(Vl + r0);
            float4 v0 = vp[0], v1 = vp[1], v2 = vp[2], v3 = vp[3];
            float vv[16] = {v0.x,v0.y,v0.z,v0.w, v1.x,v1.y,v1.z,v1.w,
                            v2.x,v2.y,v2.z,v2.w, v3.x,v3.y,v3.z,v3.w};
            #pragma unroll
            for (int jj = 0; jj < 16; ++jj) w[jj] = Crow[jj] + vv[jj];
        }
        // pairwise max tree
        float m8[8];
        #pragma unroll
        for (int k = 0; k < 8; ++k) m8[k] = fmaxf(w[k], w[k + 8]);
        float m4a = fmaxf(m8[0], m8[4]), m4b = fmaxf(m8[1], m8[5]);
        float m4c = fmaxf(m8[2], m8[6]), m4d = fmaxf(m8[3], m8[7]);
        float mx = fmaxf(fmaxf(m4a, m4b), fmaxf(m4c, m4d));
        mx = fmaxf(mx, __shfl_xor(mx, 32));

        float ex[16];
        #pragma unroll
        for (int jj = 0; jj < 16; ++jj) ex[jj] = __builtin_amdgcn_exp2f(w[jj] - mx);
        // pairwise sum trees for sm and pc
        float s8[8], p8[8];
        #pragma unroll
        for (int k = 0; k < 8; ++k) {
            s8[k] = ex[k] + ex[k + 8];
            p8[k] = fmaf(ex[k], Crow[k], ex[k + 8] * Crow[k + 8]);
        }
        float sm = ((s8[0]+s8[4]) + (s8[1]+s8[5])) + ((s8[2]+s8[6]) + (s8[3]+s8[7]));
        float pc = ((p8[0]+p8[4]) + (p8[1]+p8[5])) + ((p8[2]+p8[6]) + (p8[3]+p8[7]));
        sm += __shfl_xor(sm, 32);

        // cost of state after `it` iterations (pre-update U; V just read)
        float cc = (it > 0) ? __builtin_amdgcn_exp2f(U + mx) * pc : 0.f;

        float Un = LOGMU2 - (mx + __builtin_amdgcn_logf(sm));
        float du = fabsf(Un - U);   // identical in both halves

        // interleaved butterflies: du needs 5 levels, cc needs 6
        #pragma unroll
        for (int m = 1; m < 32; m <<= 1) {
            du += __shfl_xor(du, m);
            cc += __shfl_xor(cc, m);
        }
        cc += __shfl_xor(cc, 32);

        if (t == 0) {
            err_part[(size_t)it * (2 * nE) + b] = EPS_LN2 * du;
            if (it > 0)
                cost_all[(size_t)(it - 1) * (2 * nE) + b] = -EPS_LN2 * cc;
        }
        U = Un;
        Ul[c] = U;

        // ---- col pass ----
        float wc[16];
        {
            const float4* up = (const float4*)(Ul + r0);
            float4 u0 = up[0], u1 = up[1], u2 = up[2], u3 = up[3];
            float uu[16] = {u0.x,u0.y,u0.z,u0.w, u1.x,u1.y,u1.z,u1.w,
                            u2.x,u2.y,u2.z,u2.w, u3.x,u3.y,u3.z,u3.w};
            #pragma unroll
            for (int ii = 0; ii < 16; ++ii) wc[ii] = Ccol[ii] + uu[ii];
        }
        float n8[8];
        #pragma unroll
        for (int k = 0; k < 8; ++k) n8[k] = fmaxf(wc[k], wc[k + 8]);
        float n4a = fmaxf(n8[0], n8[4]), n4b = fmaxf(n8[1], n8[5]);
        float n4c = fmaxf(n8[2], n8[6]), n4d = fmaxf(n8[3], n8[7]);
        float mx2 = fmaxf(fmaxf(n4a, n4b), fmaxf(n4c, n4d));
        mx2 = fmaxf(mx2, __shfl_xor(mx2, 32));

        float e2[16];
        #pragma unroll
        for (int ii = 0; ii < 16; ++ii) e2[ii] = __builtin_amdgcn_exp2f(wc[ii] - mx2);
        float t8[8];
        #pragma unroll
        for (int k = 0; k < 8; ++k) t8[k] = e2[k] + e2[k + 8];
        float sm2 = ((t8[0]+t8[4]) + (t8[1]+t8[5])) + ((t8[2]+t8[6]) + (t8[3]+t8[7]));
        sm2 += __shfl_xor(sm2, 32);
        float Vn = LOGMU2 - (mx2 + __builtin_amdgcn_logf(sm2));
        Vl[c] = Vn;
    }

    // final-state cost (after MAX_ITER iterations) -> index MAX_ITER-1
    {
        const float4* vp = (const float4*)(Vl + r0);
        float4 v0 = vp[0], v1 = vp[1], v2 = vp[2], v3 = vp[3];
        float vv[16] = {v0.x,v0.y,v0.z,v0.w, v1.x,v1.y,v1.z,v1.w,
                        v2.x,v2.y,v2.z,v2.w, v3.x,v3.y,v3.z,v3.w};
        float cc = 0.f;
        #pragma unroll
        for (int jj = 0; jj < 16; ++jj)
            cc = fmaf(__builtin_amdgcn_exp2f(U + Crow[jj] + vv[jj]), Crow[jj], cc);
        #pragma unroll
        for (int m = 1; m < 64; m <<= 1) cc += __shfl_xor(cc, m);
        if (t == 0)
            cost_all[(size_t)(MAX_ITER - 1) * (2 * nE) + b] = -EPS_LN2 * cc;
    }
}

// ---------------- err reduce + final loss, last-block pattern (20 blocks) ---
__global__ __launch_bounds__(256) void err_final(
    const float* __restrict__ err_part, const float* __restrict__ cost_all,
    float* __restrict__ err_mean, unsigned* __restrict__ counter,
    float* __restrict__ out, int nE)
{
    __shared__ float red[256];
    __shared__ int is_last;

    int side = blockIdx.x / MAX_ITER;
    int it = blockIdx.x - side * MAX_ITER;
    const float* p = err_part + (size_t)it * (2 * nE) + side * nE;
    float s = 0.f;
    for (int idx = threadIdx.x; idx < nE; idx += 256) s += p[idx];
    red[threadIdx.x] = s;
    __syncthreads();
    for (int stride = 128; stride > 0; stride >>= 1) {
        if (threadIdx.x < stride) red[threadIdx.x] += red[threadIdx.x + stride];
        __syncthreads();
    }
    if (threadIdx.x == 0) {
        __hip_atomic_store(&err_mean[side * MAX_ITER + it], red[0] / (float)nE,
                           __ATOMIC_RELAXED, __HIP_MEMORY_SCOPE_AGENT);
        __threadfence();
        unsigned old = __hip_atomic_fetch_add(counter, 1u, __ATOMIC_ACQ_REL,
                                              __HIP_MEMORY_SCOPE_AGENT);
        is_last = (old == 2 * MAX_ITER - 1);
    }
    __syncthreads();
    if (!is_last) return;

    float em[2 * MAX_ITER];
    #pragma unroll
    for (int i = 0; i < 2 * MAX_ITER; ++i)
        em[i] = __hip_atomic_load(&err_mean[i], __ATOMIC_RELAXED,
                                  __HIP_MEMORY_SCOPE_AGENT);
    int Tp = MAX_ITER, Tn = MAX_ITER;
    for (int i = 0; i < MAX_ITER; ++i)
        if (em[i] < THRESH) { Tp = i + 1; break; }
    for (int i = 0; i < MAX_ITER; ++i)
        if (em[MAX_ITER + i] < THRESH) { Tn = i + 1; break; }

    float acc = 0.f;
    for (int b = threadIdx.x; b < 2 * nE; b += 256) {
        int sd = (b >= nE) ? 1 : 0;
        int T = sd ? Tn : Tp;
        float cost = cost_all[(size_t)(T - 1) * (2 * nE) + b];
        acc += sd ? expf(-cost) : cost * cost;
    }
    __syncthreads();
    red[threadIdx.x] = acc;
    __syncthreads();
    for (int stride = 128; stride > 0; stride >>= 1) {
        if (threadIdx.x < stride) red[threadIdx.x] += red[threadIdx.x + stride];
        __syncthreads();
    }
    if (threadIdx.x == 0) out[0] = red[0] / (float)nE;
}

extern "C" void kernel_launch(void* const* d_in, const int* in_sizes, int n_in,
                              void* d_out, int out_size, void* d_ws, size_t ws_size,
                              hipStream_t stream)
{
    const float* X = (const float*)d_in[0];
    const float* W = (const float*)d_in[1];
    const int* ep = (const int*)d_in[2];
    const int* en = (const int*)d_in[3];
    float* out = (float*)d_out;

    int K = in_sizes[1] / EMB;     // 256
    int M = in_sizes[0] / K;       // 10000
    int nE = in_sizes[2] / 2;      // 4096

    float* ws = (float*)d_ws;
    float* Z = ws;                                          // M*EMB f32
    float* err_part = Z + (size_t)M * EMB;                  // MAX_ITER*2nE
    float* cost_all = err_part + (size_t)MAX_ITER * 2 * nE; // MAX_ITER*2nE
    float* err_mean = cost_all + (size_t)MAX_ITER * 2 * nE; // 32 (20 used)
    unsigned* counter = (unsigned*)(err_mean + 32);         // 1 u32

    dim3 gg((M + 63) / 64, EMB / 64);
    gemm_fused<<<gg, 256, 0, stream>>>(X, W, Z, M, K, EMB, counter);

    int nblk = (2 * nE) / WPB;
    sinkhorn_fused<<<nblk, 64 * WPB, 0, stream>>>(Z, ep, en, nE, err_part, cost_all);

    err_final<<<2 * MAX_ITER, 256, 0, stream>>>(err_part, cost_all, err_mean,
                                                counter, out, nE);
}

// Round 13
// 144.795 us; speedup vs baseline: 1.4057x; 1.0170x over previous
//
#include <hip/hip_runtime.h>
#include <hip/hip_bf16.h>
#include <math.h>

#define N_POINTS 32
#define SPACE_DIM 16
#define EMB 512
#define THRESH 0.1f
#define MAX_ITER 10

// log2-domain constants
#define NEG10LOG2E -14.42695040888963f   // -10*log2(e): C -> Crow2
#define EPS_LN2     0.0693147180559945f  // eps*ln2
#define LOGMU2     -4.99999953834f       // log2(1/32 + 1e-8)

typedef _Float16 half8 __attribute__((ext_vector_type(8)));
typedef _Float16 half4 __attribute__((ext_vector_type(4)));
typedef float floatx4 __attribute__((ext_vector_type(4)));

#define BSTRIDE 264   // halves; 528 B rows -> b128-aligned, 2-way max (free)

// ---------------- Fused GEMM: Z = X @ W (fp32 in, f16 MFMA, fp32 out) -------
__global__ __launch_bounds__(256) void gemm_fused(
    const float* __restrict__ X, const float* __restrict__ W,
    float* __restrict__ Z, int M, int K, int N, unsigned* __restrict__ counter)
{
    // zero the err_final counter (visible to err_final via kernel boundary)
    if (blockIdx.x == 0 && blockIdx.y == 0 && threadIdx.x == 0) counter[0] = 0u;

    __shared__ _Float16 Bs[64][BSTRIDE];   // [n][k]

    int t = threadIdx.x;
    int n0 = blockIdx.y * 64;

    // stage W-tile (256k x 64n fp32) -> Bs[n][k] f16, 4x4 sub-blocks
    #pragma unroll
    for (int s = 0; s < 4; ++s) {
        int u = s * 256 + t;
        int nb = u & 15;          // n-group (4 cols)
        int kb = u >> 4;          // k-group (4 rows)
        float4 r0v = *(const float4*)&W[(size_t)(kb * 4 + 0) * N + n0 + nb * 4];
        float4 r1v = *(const float4*)&W[(size_t)(kb * 4 + 1) * N + n0 + nb * 4];
        float4 r2v = *(const float4*)&W[(size_t)(kb * 4 + 2) * N + n0 + nb * 4];
        float4 r3v = *(const float4*)&W[(size_t)(kb * 4 + 3) * N + n0 + nb * 4];
        float c0[4] = {r0v.x, r0v.y, r0v.z, r0v.w};
        float c1[4] = {r1v.x, r1v.y, r1v.z, r1v.w};
        float c2[4] = {r2v.x, r2v.y, r2v.z, r2v.w};
        float c3[4] = {r3v.x, r3v.y, r3v.z, r3v.w};
        #pragma unroll
        for (int c = 0; c < 4; ++c) {
            half4 h = {(_Float16)c0[c], (_Float16)c1[c],
                       (_Float16)c2[c], (_Float16)c3[c]};
            *(half4*)&Bs[nb * 4 + c][kb * 4] = h;
        }
    }
    __syncthreads();

    int wave = t >> 6;
    int lane = t & 63;
    int quad = lane >> 4;
    int l16 = lane & 15;

    int mrow = blockIdx.x * 64 + wave * 16 + l16;
    int msafe = mrow < M ? mrow : M - 1;
    const float4* xp = (const float4*)(X + (size_t)msafe * K);

    floatx4 acc[4] = {{0.f,0.f,0.f,0.f},{0.f,0.f,0.f,0.f},
                      {0.f,0.f,0.f,0.f},{0.f,0.f,0.f,0.f}};

    for (int k0 = 0; k0 < K; k0 += 32) {
        float4 lo = xp[(k0 >> 2) + quad * 2];
        float4 hi = xp[(k0 >> 2) + quad * 2 + 1];
        half8 a = {(_Float16)lo.x, (_Float16)lo.y, (_Float16)lo.z, (_Float16)lo.w,
                   (_Float16)hi.x, (_Float16)hi.y, (_Float16)hi.z, (_Float16)hi.w};
        #pragma unroll
        for (int ct = 0; ct < 4; ++ct) {
            half8 b = *(const half8*)&Bs[ct * 16 + l16][k0 + quad * 8];
            acc[ct] = __builtin_amdgcn_mfma_f32_16x16x32_f16(a, b, acc[ct], 0, 0, 0);
        }
    }

    int rbase = blockIdx.x * 64 + wave * 16 + quad * 4;
    #pragma unroll
    for (int ct = 0; ct < 4; ++ct) {
        int col = n0 + ct * 16 + l16;
        #pragma unroll
        for (int r = 0; r < 4; ++r) {
            int row = rbase + r;
            if (row < M) Z[(size_t)row * N + col] = acc[ct][r];
        }
    }
}

// ---------------- Fused Sinkhorn: 4 edges/block, 1 wave/edge, log2 domain ---
// R12 body + FULL UNROLL + register-banked per-iter partials; all cross-lane
// butterflies deferred to one post-loop interleaved block (20 independent
// chains hide shuffle latency). Plain stores, zero atomics, zero barriers.
#define WPB 4

__global__ __launch_bounds__(256, 4) void sinkhorn_fused(
    const float* __restrict__ Z,
    const int* __restrict__ ep, const int* __restrict__ en,
    int nE,
    float* __restrict__ err_part,   // [MAX_ITER][2nE]
    float* __restrict__ cost_all)   // [MAX_ITER][2nE]
{
    __shared__ float shm[WPB][32 * 36];  // union: sb=32x20, csh=32x36
    __shared__ float uvs[WPB][64];       // U2[0:32], V2[32:64]

    int tid = threadIdx.x;
    int wv = tid >> 6;
    int t = tid & 63;
    int b = blockIdx.x * WPB + wv;

    int side = (b >= nE) ? 1 : 0;
    int e = b - side * nE;
    const int* edges = side ? en : ep;
    int nx = edges[e];
    int ny = edges[e + nE];

    int c = t & 31;
    int h = t >> 5;
    int r0 = h * 16;

    float* sb  = shm[wv];
    float* csh = shm[wv];
    float* Ul  = uvs[wv];
    float* Vl  = uvs[wv] + 32;

    // stage b point rows into LDS, padded stride 20
    {
        const float4* zb4 = (const float4*)(Z + (size_t)ny * EMB);
        float4 q0 = zb4[t * 2];
        float4 q1 = zb4[t * 2 + 1];
        float* dst = sb + (t >> 1) * 20 + (t & 1) * 8;
        ((float4*)dst)[0] = q0;
        ((float4*)dst)[1] = q1;
    }
    // own a-row in registers
    float areg[16];
    {
        const float4* za4 = (const float4*)(Z + (size_t)nx * EMB + c * SPACE_DIM);
        float4 a0 = za4[0], a1 = za4[1], a2 = za4[2], a3 = za4[3];
        areg[0]=a0.x; areg[1]=a0.y; areg[2]=a0.z; areg[3]=a0.w;
        areg[4]=a1.x; areg[5]=a1.y; areg[6]=a1.z; areg[7]=a1.w;
        areg[8]=a2.x; areg[9]=a2.y; areg[10]=a2.z; areg[11]=a2.w;
        areg[12]=a3.x; areg[13]=a3.y; areg[14]=a3.z; areg[15]=a3.w;
    }

    // Crow[jj] = -10*log2e * ||a_c - b_{r0+jj}||^2
    float Crow[16];
    #pragma unroll
    for (int jj = 0; jj < 16; ++jj) {
        const float* bp = sb + (r0 + jj) * 20;
        float s = 0.f;
        #pragma unroll
        for (int d = 0; d < SPACE_DIM; ++d) {
            float diff = areg[d] - bp[d];
            s = fmaf(diff, diff, s);
        }
        Crow[jj] = s * NEG10LOG2E;
    }
    // transpose through LDS (stride 36) to get column fragment
    #pragma unroll
    for (int g = 0; g < 4; ++g) {
        *(float4*)&csh[c * 36 + r0 + g * 4] =
            make_float4(Crow[g*4+0], Crow[g*4+1], Crow[g*4+2], Crow[g*4+3]);
    }
    float Ccol[16];
    #pragma unroll
    for (int ii = 0; ii < 16; ++ii)
        Ccol[ii] = csh[(r0 + ii) * 36 + c];

    Vl[c] = 0.f;
    float U = 0.f;
    float ccp[MAX_ITER];   // per-lane cost partials (state after iter k+1)
    float dup[MAX_ITER];   // per-lane du of iter k (duplicated across halves)

    #pragma unroll        // FULL unroll: ccp/dup indices static -> VGPRs
    for (int it = 0; it < MAX_ITER; ++it) {
        // ---- row pass ----
        float w[16];
        {
            const float4* vp = (const float4*)(Vl + r0);
            float4 v0 = vp[0], v1 = vp[1], v2 = vp[2], v3 = vp[3];
            float vv[16] = {v0.x,v0.y,v0.z,v0.w, v1.x,v1.y,v1.z,v1.w,
                            v2.x,v2.y,v2.z,v2.w, v3.x,v3.y,v3.z,v3.w};
            #pragma unroll
            for (int jj = 0; jj < 16; ++jj) w[jj] = Crow[jj] + vv[jj];
        }
        // pairwise max tree
        float m8[8];
        #pragma unroll
        for (int k = 0; k < 8; ++k) m8[k] = fmaxf(w[k], w[k + 8]);
        float m4a = fmaxf(m8[0], m8[4]), m4b = fmaxf(m8[1], m8[5]);
        float m4c = fmaxf(m8[2], m8[6]), m4d = fmaxf(m8[3], m8[7]);
        float mx = fmaxf(fmaxf(m4a, m4b), fmaxf(m4c, m4d));
        mx = fmaxf(mx, __shfl_xor(mx, 32));

        float ex[16];
        #pragma unroll
        for (int jj = 0; jj < 16; ++jj) ex[jj] = __builtin_amdgcn_exp2f(w[jj] - mx);
        // pairwise sum trees for sm and pc
        float s8[8], p8[8];
        #pragma unroll
        for (int k = 0; k < 8; ++k) {
            s8[k] = ex[k] + ex[k + 8];
            p8[k] = fmaf(ex[k], Crow[k], ex[k + 8] * Crow[k + 8]);
        }
        float sm = ((s8[0]+s8[4]) + (s8[1]+s8[5])) + ((s8[2]+s8[6]) + (s8[3]+s8[7]));
        float pc = ((p8[0]+p8[4]) + (p8[1]+p8[5])) + ((p8[2]+p8[6]) + (p8[3]+p8[7]));
        sm += __shfl_xor(sm, 32);

        // per-lane cost partial of state after `it` iterations (pre-update U)
        if (it > 0) ccp[it - 1] = __builtin_amdgcn_exp2f(U + mx) * pc;

        float Un = LOGMU2 - (mx + __builtin_amdgcn_logf(sm));
        dup[it] = fabsf(Un - U);   // identical in both halves
        U = Un;
        Ul[c] = U;

        // ---- col pass ----
        float wc[16];
        {
            const float4* up = (const float4*)(Ul + r0);
            float4 u0 = up[0], u1 = up[1], u2 = up[2], u3 = up[3];
            float uu[16] = {u0.x,u0.y,u0.z,u0.w, u1.x,u1.y,u1.z,u1.w,
                            u2.x,u2.y,u2.z,u2.w, u3.x,u3.y,u3.z,u3.w};
            #pragma unroll
            for (int ii = 0; ii < 16; ++ii) wc[ii] = Ccol[ii] + uu[ii];
        }
        float n8[8];
        #pragma unroll
        for (int k = 0; k < 8; ++k) n8[k] = fmaxf(wc[k], wc[k + 8]);
        float n4a = fmaxf(n8[0], n8[4]), n4b = fmaxf(n8[1], n8[5]);
        float n4c = fmaxf(n8[2], n8[6]), n4d = fmaxf(n8[3], n8[7]);
        float mx2 = fmaxf(fmaxf(n4a, n4b), fmaxf(n4c, n4d));
        mx2 = fmaxf(mx2, __shfl_xor(mx2, 32));

        float e2[16];
        #pragma unroll
        for (int ii = 0; ii < 16; ++ii) e2[ii] = __builtin_amdgcn_exp2f(wc[ii] - mx2);
        float t8[8];
        #pragma unroll
        for (int k = 0; k < 8; ++k) t8[k] = e2[k] + e2[k + 8];
        float sm2 = ((t8[0]+t8[4]) + (t8[1]+t8[5])) + ((t8[2]+t8[6]) + (t8[3]+t8[7]));
        sm2 += __shfl_xor(sm2, 32);
        float Vn = LOGMU2 - (mx2 + __builtin_amdgcn_logf(sm2));
        Vl[c] = Vn;
    }

    // final-state cost partial -> ccp[MAX_ITER-1]
    {
        const float4* vp = (const float4*)(Vl + r0);
        float4 v0 = vp[0], v1 = vp[1], v2 = vp[2], v3 = vp[3];
        float vv[16] = {v0.x,v0.y,v0.z,v0.w, v1.x,v1.y,v1.z,v1.w,
                        v2.x,v2.y,v2.z,v2.w, v3.x,v3.y,v3.z,v3.w};
        float cc = 0.f;
        #pragma unroll
        for (int jj = 0; jj < 16; ++jj)
            cc = fmaf(__builtin_amdgcn_exp2f(U + Crow[jj] + vv[jj]), Crow[jj], cc);
        ccp[MAX_ITER - 1] = cc;
    }

    // post-loop: 20 independent butterfly chains, latencies overlap
    #pragma unroll
    for (int m = 1; m < 32; m <<= 1) {
        #pragma unroll
        for (int k = 0; k < MAX_ITER; ++k) {
            dup[k] += __shfl_xor(dup[k], m);
            ccp[k] += __shfl_xor(ccp[k], m);
        }
    }
    #pragma unroll
    for (int k = 0; k < MAX_ITER; ++k) ccp[k] += __shfl_xor(ccp[k], 32);

    if (t == 0) {
        #pragma unroll
        for (int k = 0; k < MAX_ITER; ++k)
            err_part[(size_t)k * (2 * nE) + b] = EPS_LN2 * dup[k];
        #pragma unroll
        for (int k = 0; k < MAX_ITER; ++k)
            cost_all[(size_t)k * (2 * nE) + b] = -EPS_LN2 * ccp[k];
    }
}

// ---------------- err reduce + final loss, last-block pattern (20 blocks) ---
__global__ __launch_bounds__(256) void err_final(
    const float* __restrict__ err_part, const float* __restrict__ cost_all,
    float* __restrict__ err_mean, unsigned* __restrict__ counter,
    float* __restrict__ out, int nE)
{
    __shared__ float red[256];
    __shared__ int is_last;

    int side = blockIdx.x / MAX_ITER;
    int it = blockIdx.x - side * MAX_ITER;
    const float* p = err_part + (size_t)it * (2 * nE) + side * nE;
    float s = 0.f;
    for (int idx = threadIdx.x; idx < nE; idx += 256) s += p[idx];
    red[threadIdx.x] = s;
    __syncthreads();
    for (int stride = 128; stride > 0; stride >>= 1) {
        if (threadIdx.x < stride) red[threadIdx.x] += red[threadIdx.x + stride];
        __syncthreads();
    }
    if (threadIdx.x == 0) {
        __hip_atomic_store(&err_mean[side * MAX_ITER + it], red[0] / (float)nE,
                           __ATOMIC_RELAXED, __HIP_MEMORY_SCOPE_AGENT);
        __threadfence();
        unsigned old = __hip_atomic_fetch_add(counter, 1u, __ATOMIC_ACQ_REL,
                                              __HIP_MEMORY_SCOPE_AGENT);
        is_last = (old == 2 * MAX_ITER - 1);
    }
    __syncthreads();
    if (!is_last) return;

    float em[2 * MAX_ITER];
    #pragma unroll
    for (int i = 0; i < 2 * MAX_ITER; ++i)
        em[i] = __hip_atomic_load(&err_mean[i], __ATOMIC_RELAXED,
                                  __HIP_MEMORY_SCOPE_AGENT);
    int Tp = MAX_ITER, Tn = MAX_ITER;
    for (int i = 0; i < MAX_ITER; ++i)
        if (em[i] < THRESH) { Tp = i + 1; break; }
    for (int i = 0; i < MAX_ITER; ++i)
        if (em[MAX_ITER + i] < THRESH) { Tn = i + 1; break; }

    float acc = 0.f;
    for (int b = threadIdx.x; b < 2 * nE; b += 256) {
        int sd = (b >= nE) ? 1 : 0;
        int T = sd ? Tn : Tp;
        float cost = cost_all[(size_t)(T - 1) * (2 * nE) + b];
        acc += sd ? expf(-cost) : cost * cost;
    }
    __syncthreads();
    red[threadIdx.x] = acc;
    __syncthreads();
    for (int stride = 128; stride > 0; stride >>= 1) {
        if (threadIdx.x < stride) red[threadIdx.x] += red[threadIdx.x + stride];
        __syncthreads();
    }
    if (threadIdx.x == 0) out[0] = red[0] / (float)nE;
}

extern "C" void kernel_launch(void* const* d_in, const int* in_sizes, int n_in,
                              void* d_out, int out_size, void* d_ws, size_t ws_size,
                              hipStream_t stream)
{
    const float* X = (const float*)d_in[0];
    const float* W = (const float*)d_in[1];
    const int* ep = (const int*)d_in[2];
    const int* en = (const int*)d_in[3];
    float* out = (float*)d_out;

    int K = in_sizes[1] / EMB;     // 256
    int M = in_sizes[0] / K;       // 10000
    int nE = in_sizes[2] / 2;      // 4096

    float* ws = (float*)d_ws;
    float* Z = ws;                                          // M*EMB f32
    float* err_part = Z + (size_t)M * EMB;                  // MAX_ITER*2nE
    float* cost_all = err_part + (size_t)MAX_ITER * 2 * nE; // MAX_ITER*2nE
    float* err_mean = cost_all + (size_t)MAX_ITER * 2 * nE; // 32 (20 used)
    unsigned* counter = (unsigned*)(err_mean + 32);         // 1 u32

    dim3 gg((M + 63) / 64, EMB / 64);
    gemm_fused<<<gg, 256, 0, stream>>>(X, W, Z, M, K, EMB, counter);

    int nblk = (2 * nE) / WPB;
    sinkhorn_fused<<<nblk, 64 * WPB, 0, stream>>>(Z, ep, en, nE, err_part, cost_all);

    err_final<<<2 * MAX_ITER, 256, 0, stream>>>(err_part, cost_all, err_mean,
                                                counter, out, nE);
}